// Round 16
// baseline (110.420 us; speedup 1.0000x reference)
//
#include <hip/hip_runtime.h>
#include <math.h>
#include <float.h>
#include <limits.h>

#define NBATCH 4
#define NPROP  4096
#define NCLS   91
#define NFG    90
#define NDET   100
#define CCAP   1024            // per-(image,class) candidate cap (avg ~80; never hit)
#define BN     (NBATCH * NPROP)
#define SLOTS  (NFG * NDET)    // 9000 survivor slots per image
#define FCAP   16384           // fallback sort capacity (pow2 >= SLOTS)
#define CHUNK  128             // NMS matrix-walk chunk size
#define CSRCAP (NPROP * 19)    // provable max candidates per image (softmax bound)

static __device__ __forceinline__ float clampf(float x, float lo, float hi) {
    return fminf(fmaxf(x, lo), hi);
}

// Decode + clip one (proposal, class) box. Identical arithmetic everywhere it is
// used -> bitwise-identical results (validated absmax 0.0, R1-R15).
static __device__ __forceinline__ void decode_box(int b, int np, int c,
    const float* __restrict__ props, const float* __restrict__ deltas,
    float W, float H, float& bx1, float& by1, float& bx2, float& by2)
{
    const float* pr = props + ((size_t)b * NPROP + np) * 4;
    const float x1 = pr[0], y1 = pr[1], x2 = pr[2], y2 = pr[3];
    const float w = x2 - x1, h = y2 - y1;
    const float cx = x1 + 0.5f * w, cy = y1 + 0.5f * h;
    const float* d = deltas + (((size_t)b * NPROP + np) * NCLS + c) * 4;
    const float BBC = 4.135166556742356f;   // log(1000/16)
    const float dx = d[0] / 10.0f;
    const float dy = d[1] / 10.0f;
    const float dw = fminf(d[2] / 5.0f, BBC);
    const float dh = fminf(d[3] / 5.0f, BBC);
    const float pcx = dx * w + cx;
    const float pcy = dy * h + cy;
    const float pw = expf(dw) * w;
    const float ph = expf(dh) * h;
    bx1 = clampf(pcx - 0.5f * pw, 0.0f, W);
    by1 = clampf(pcy - 0.5f * ph, 0.0f, H);
    bx2 = clampf(pcx + 0.5f * pw, 0.0f, W);
    by2 = clampf(pcy + 0.5f * ph, 0.0f, H);
}

// IoU > 0.5 predicate, identical float expression to all validated rounds.
static __device__ __forceinline__ bool iou_gt(const float4 S, const float4 Q, float aq)
{
    const float iw = fmaxf(fminf(S.z, Q.z) - fmaxf(S.x, Q.x), 0.0f);
    const float ih = fmaxf(fminf(S.w, Q.w) - fmaxf(S.y, Q.y), 0.0f);
    const float inter = iw * ih;
    const float as = (S.z - S.x) * (S.w - S.y);
    return inter / (as + aq - inter) > 0.5f;
}

// Block-wide exclusive scan over 1024 threads (wave shfl scan + wave totals).
static __device__ __forceinline__ int block_excl_scan(int v, int t, int* wtot)
{
    const int lane = t & 63, wid = t >> 6;
    int inc = v;
    #pragma unroll
    for (int s = 1; s < 64; s <<= 1) {
        const int u = __shfl_up(inc, s);
        if (lane >= s) inc += u;
    }
    if (lane == 63) wtot[wid] = inc;
    __syncthreads();
    int base = 0;
    for (int w2 = 0; w2 < wid; ++w2) base += wtot[w2];
    __syncthreads();                 // protect wtot for the next call
    return base + inc - v;
}

// Kernel 1: per-proposal softmax stats + 91-bit FINAL candidate mask.
// UNCHANGED from validated R9-R15.
__global__ __launch_bounds__(256) void stats_mask_kernel(
    const float* __restrict__ logits, const float* __restrict__ props,
    const float* __restrict__ deltas, const int* __restrict__ imgsh,
    float2* __restrict__ stats, unsigned* __restrict__ mask)
{
    const int wavei = threadIdx.x >> 6;
    const int lane  = threadIdx.x & 63;
    const int p = blockIdx.x * 4 + wavei;          // 0 .. B*N-1
    const int b = p >> 12;
    const int np = p & (NPROP - 1);
    const float* lrow = logits + (size_t)p * NCLS;

    const float a  = lrow[lane];
    const float a2 = (lane + 64 < NCLS) ? lrow[lane + 64] : -INFINITY;

    float m = fmaxf(a, a2);                        // level s=64
    #pragma unroll
    for (int s = 32; s > 0; s >>= 1) m = fmaxf(m, __shfl_down(m, s));
    m = __shfl(m, 0);

    const float e0 = expf(a - m);
    const float e1 = (lane + 64 < NCLS) ? expf(a2 - m) : 0.0f;
    float sum = e0 + e1;                           // level s=64
    #pragma unroll
    for (int s = 32; s > 0; s >>= 1) sum += __shfl_down(sum, s);
    sum = __shfl(sum, 0);

    const float W = (float)imgsh[b * 2 + 1];
    const float H = (float)imgsh[b * 2 + 0];

    bool pass0 = ((e0 / sum) > 0.05f) && (lane >= 1);     // class = lane (skip bg 0)
    if (pass0) {
        float bx1, by1, bx2, by2;
        decode_box(b, np, lane, props, deltas, W, H, bx1, by1, bx2, by2);
        pass0 = ((bx2 - bx1) >= 0.01f) && ((by2 - by1) >= 0.01f);
    }
    bool pass1 = ((e1 / sum) > 0.05f);                    // class = lane+64 (<= 90)
    if (pass1) {
        float bx1, by1, bx2, by2;
        decode_box(b, np, lane + 64, props, deltas, W, H, bx1, by1, bx2, by2);
        pass1 = ((bx2 - bx1) >= 0.01f) && ((by2 - by1) >= 0.01f);
    }

    const unsigned long long b0 = __ballot(pass0);        // classes 0..63
    const unsigned long long b1 = __ballot(pass1);        // classes 64..90

    if (lane == 0) {
        stats[p] = make_float2(m, sum);
        mask[p]          = (unsigned)b0;           // plane 0: classes  0..31
        mask[BN + p]     = (unsigned)(b0 >> 32);   // plane 1: classes 32..63
        mask[2 * BN + p] = (unsigned)b1;           // plane 2: classes 64..90
    }
}

// Kernel 2: one block (1024 threads) per IMAGE. Builds per-class CSR candidate
// key lists ONCE (replaces 90 blocks x 2 full mask scans).
//   phase 1: LDS-atomic class histogram from mask bits (counts deterministic)
//   scan:    Hillis-Steele over 90 -> exact per-class offsets (deterministic)
//   phase 2: compute keys (bitwise-identical score expr), place via LDS fill
//            counters. In-bucket order is atomic-nondeterministic, but the SET
//            is deterministic; kernel 3's rank-sort is a pure function of the
//            unique-key set -> canonical order downstream (R5/R15 validated).
__global__ __launch_bounds__(1024) void csr_kernel(
    const float* __restrict__ logits, const float2* __restrict__ stats,
    const unsigned* __restrict__ mask,
    int* __restrict__ clsCnt, int* __restrict__ clsOff,
    unsigned long long* __restrict__ cKeys)
{
    const int b = blockIdx.x;
    const int t = threadIdx.x;
    __shared__ int hcnt[NFG];
    __shared__ int hoff[NFG];
    __shared__ int hfill[NFG];
    __shared__ int scanbuf[128];

    if (t < NFG) { hcnt[t] = 0; hfill[t] = 0; }
    __syncthreads();

    // ---- phase 1: class histogram ----
    for (int np = t; np < NPROP; np += 1024) {
        const int p = b * NPROP + np;
        unsigned m0 = mask[p];
        unsigned m1 = mask[BN + p];
        unsigned m2 = mask[2 * BN + p];
        while (m0) { const int c = __ffs(m0) - 1; m0 &= m0 - 1; atomicAdd(&hcnt[c - 1], 1); }
        while (m1) { const int c = __ffs(m1) - 1 + 32; m1 &= m1 - 1; atomicAdd(&hcnt[c - 1], 1); }
        while (m2) { const int c = __ffs(m2) - 1 + 64; m2 &= m2 - 1; atomicAdd(&hcnt[c - 1], 1); }
    }
    __syncthreads();

    // ---- exclusive scan over 90 class counts (Hillis-Steele on 128) ----
    if (t < 128) scanbuf[t] = (t < NFG) ? hcnt[t] : 0;
    __syncthreads();
    for (int s = 1; s < 128; s <<= 1) {
        int v = 0;
        if (t < 128 && t >= s) v = scanbuf[t - s];
        __syncthreads();
        if (t < 128) scanbuf[t] += v;
        __syncthreads();
    }
    if (t < NFG) {
        hoff[t] = scanbuf[t] - hcnt[t];            // exclusive offset
        clsCnt[b * NFG + t] = hcnt[t];
        clsOff[b * NFG + t] = hoff[t];
    }
    __syncthreads();

    // ---- phase 2: compute keys, place into class buckets ----
    unsigned long long* dst = cKeys + (size_t)b * CSRCAP;
    for (int np = t; np < NPROP; np += 1024) {
        const int p = b * NPROP + np;
        unsigned m0 = mask[p];
        unsigned m1 = mask[BN + p];
        unsigned m2 = mask[2 * BN + p];
        if (!(m0 | m1 | m2)) continue;
        const float2 st = stats[p];
        const float* lrow = logits + (size_t)p * NCLS;
        #define EMIT(c_) { \
            const int cm1_ = (c_) - 1; \
            const float score_ = expf(lrow[(c_)] - st.x) / st.y; \
            const unsigned flat_ = (unsigned)(np * NFG + cm1_); \
            const unsigned long long key_ = \
                ((unsigned long long)__float_as_uint(score_) << 32) | (unsigned)(~flat_); \
            const int pos_ = atomicAdd(&hfill[cm1_], 1); \
            dst[hoff[cm1_] + pos_] = key_; }
        while (m0) { const int c = __ffs(m0) - 1; m0 &= m0 - 1; EMIT(c); }
        while (m1) { const int c = __ffs(m1) - 1 + 32; m1 &= m1 - 1; EMIT(c); }
        while (m2) { const int c = __ffs(m2) - 1 + 64; m2 &= m2 - 1; EMIT(c); }
        #undef EMIT
    }
}

// Kernel 3: one block (256 threads) per (image, class). CSR load (coalesced,
// ~n<=few hundred) -> rank-sort (R15-validated) -> decode -> chunked
// suppression-matrix greedy NMS (R14-validated).
__global__ __launch_bounds__(256) void class_nms_kernel(
    const int* __restrict__ clsCnt, const int* __restrict__ clsOff,
    const unsigned long long* __restrict__ cKeys,
    const float* __restrict__ props, const float* __restrict__ deltas,
    const int* __restrict__ imgsh, unsigned long long* __restrict__ svKeys)
{
    const int blk  = blockIdx.x;                   // 0..359
    const int b    = blk / NFG;
    const int cm1  = blk % NFG;                    // class - 1
    const int c    = cm1 + 1;
    const int t    = threadIdx.x;

    __shared__ unsigned long long sk[CCAP];        // 8 KB, gathered (unsorted)
    __shared__ unsigned long long sks[CCAP];       // 8 KB, sorted desc
    __shared__ float4 sbox[CCAP];                  // 16 KB (boxes of sorted keys)
    __shared__ unsigned long long mrow[CHUNK][2];  // 2 KB in-chunk suppression matrix
    __shared__ float4 sOwn[NDET];                  // 1.6 KB accepted survivor boxes
    __shared__ unsigned long long sPreW[2];
    __shared__ int s_ns;

    const int n = min(clsCnt[blk], CCAP);
    if (n == 0) {
        for (int i = t; i < NDET; i += 256) svKeys[(size_t)blk * NDET + i] = 0ULL;
        return;
    }
    const unsigned long long* src = cKeys + (size_t)b * CSRCAP + clsOff[blk];
    for (int i = t; i < n; i += 256) sk[i] = src[i];
    __syncthreads();

    // ---- rank-by-counting sort (descending); unique keys -> bijective ranks ----
    {
        unsigned long long myk[4];
        int rnk[4] = {0, 0, 0, 0};
        #pragma unroll
        for (int e = 0; e < 4; ++e)
            myk[e] = (t + e * 256 < n) ? sk[t + e * 256] : 0ULL;
        #pragma unroll 4
        for (int j = 0; j < n; ++j) {
            const unsigned long long kj = sk[j];
            #pragma unroll
            for (int e = 0; e < 4; ++e) rnk[e] += (kj > myk[e]) ? 1 : 0;
        }
        #pragma unroll
        for (int e = 0; e < 4; ++e)
            if (t + e * 256 < n) sks[rnk[e]] = myk[e];
    }
    __syncthreads();

    // ---- decode boxes ONCE for sorted candidates ----
    const float W = (float)imgsh[b * 2 + 1];
    const float H = (float)imgsh[b * 2 + 0];
    for (int i = t; i < n; i += 256) {
        const unsigned flat = ~(unsigned)sks[i];
        const int np = flat / NFG;                 // flat % NFG == cm1 by construction
        float bx1, by1, bx2, by2;
        decode_box(b, np, c, props, deltas, W, H, bx1, by1, bx2, by2);
        sbox[i] = make_float4(bx1, by1, bx2, by2);
    }
    if (t == 0) s_ns = 0;
    __syncthreads();

    // ---- chunked suppression-matrix greedy NMS (R14/R15-validated) ----
    int nsTot = 0;
    for (int cb = 0; cb < n && nsTot < NDET; cb += CHUNK) {
        const int C = min(CHUNK, n - cb);

        // (a) pre-suppression vs accepted survivors (free on chunk 1: nsTot==0)
        bool pre = false;
        if (t < C) {
            const float4 Q = sbox[cb + t];
            const float aq = (Q.z - Q.x) * (Q.w - Q.y);
            for (int l = 0; l < nsTot; ++l) {
                if (iou_gt(sOwn[l], Q, aq)) { pre = true; break; }
            }
        }
        const unsigned long long bal = __ballot(pre);
        if (t == 0)  sPreW[0] = bal;               // chunk idx 0..63
        if (t == 64) sPreW[1] = bal;               // chunk idx 64..127

        // (b) in-chunk suppression matrix: thread t -> row r = t>>1, word w = t&1
        {
            const int r = t >> 1, w = t & 1;
            unsigned long long word = 0ULL;
            if (r < C) {
                const float4 R = sbox[cb + r];     // row box (the earlier/suppressor)
                const int j0 = w * 64;
                const int jend = min(j0 + 64, C);
                for (int j = (j0 > r + 1 ? j0 : r + 1); j < jend; ++j) {
                    const float4 Q = sbox[cb + j];
                    const float aq = (Q.z - Q.x) * (Q.w - Q.y);
                    if (iou_gt(R, Q, aq)) word |= (1ULL << (j - j0));
                }
            }
            mrow[r][w] = word;
        }
        __syncthreads();

        // (c) scalar bitmask walk (thread 0): ~30-40 cy/step, prefetched rows
        if (t == 0) {
            unsigned long long S0 = sPreW[0], S1 = sPreW[1];
            int ns = nsTot;
            unsigned long long r0 = mrow[0][0], r1 = mrow[0][1];
            for (int i = 0; i < C && ns < NDET; ++i) {
                const unsigned long long nr0 = (i + 1 < C) ? mrow[i + 1][0] : 0ULL;
                const unsigned long long nr1 = (i + 1 < C) ? mrow[i + 1][1] : 0ULL;
                const bool dead = (i < 64) ? ((S0 >> i) & 1ULL)
                                           : ((S1 >> (i - 64)) & 1ULL);
                if (!dead) {
                    sOwn[ns] = sbox[cb + i];
                    svKeys[(size_t)blk * NDET + ns] = sks[cb + i];
                    ++ns;
                    S0 |= r0; S1 |= r1;
                }
                r0 = nr0; r1 = nr1;
            }
            s_ns = ns;
        }
        __syncthreads();
        nsTot = s_ns;
    }

    // zero-fill unused survivor slots (deterministic)
    for (int i = nsTot + t; i < NDET; i += 256) svKeys[(size_t)blk * NDET + i] = 0ULL;
}

// Kernel 4: radix-select top-100. UNCHANGED from validated R12-R15.
__global__ __launch_bounds__(1024) void select_kernel(
    const unsigned long long* __restrict__ svKeys,
    const float* __restrict__ props, const float* __restrict__ deltas,
    const int* __restrict__ imgsh, float* __restrict__ out)
{
    const int b = blockIdx.x;
    const int t = threadIdx.x;
    __shared__ unsigned long long F[FCAP];         // 128 KB (sort buffer)
    __shared__ int hist[4096];                     // 16 KB
    __shared__ int wtot[16];
    __shared__ int s_T, s_above, s_total;

    if (t == 0) { s_T = -1; s_above = 0; s_total = 0; }
    #pragma unroll
    for (int j = 0; j < 4; ++j) hist[t + j * 1024] = 0;

    const unsigned long long* src = svKeys + (size_t)b * SLOTS;
    unsigned long long keys[9];
    #pragma unroll
    for (int j = 0; j < 9; ++j) {
        const int s = t + j * 1024;
        keys[j] = (s < SLOTS) ? src[s] : 0ULL;
    }
    __syncthreads();

    #pragma unroll
    for (int j = 0; j < 9; ++j) {
        if (keys[j] != 0ULL) atomicAdd(&hist[(unsigned)(keys[j] >> 52)], 1);
    }
    __syncthreads();

    {
        const int gbase = (1023 - t) * 4;
        const int s0 = hist[gbase] + hist[gbase + 1] + hist[gbase + 2] + hist[gbase + 3];
        const int pre = block_excl_scan(s0, t, wtot);   // counts in all higher buckets
        int acc = pre;
        for (int d = gbase + 3; d >= gbase; --d) {
            const int h = hist[d];
            if (acc < NDET && acc + h >= NDET) { s_T = d; s_above = acc; }  // unique
            acc += h;
        }
        if (t == 1023) s_total = acc;              // lowest group finishes the total
    }
    __syncthreads();

    const int T = s_T;
    const int total = s_total;
    const int n2 = (T < 0) ? total : (s_above + hist[T]);
    const bool fast = (n2 <= 2048);

    int mycnt = 0;
    #pragma unroll
    for (int j = 0; j < 9; ++j) {
        const unsigned long long k = keys[j];
        const bool m = (k != 0ULL) && (fast ? (T < 0 || (int)(k >> 52) >= T) : true);
        mycnt += m ? 1 : 0;
    }
    int off = block_excl_scan(mycnt, t, wtot);
    #pragma unroll
    for (int j = 0; j < 9; ++j) {
        const unsigned long long k = keys[j];
        const bool m = (k != 0ULL) && (fast ? (T < 0 || (int)(k >> 52) >= T) : true);
        if (m) F[off++] = k;
    }
    const int nsort = fast ? n2 : total;

    int P = 128; while (P < nsort) P <<= 1;        // pow2 pad, >= 128, <= FCAP
    for (int i = nsort + t; i < P; i += 1024) F[i] = 0ULL;

    for (unsigned kk = 2; kk <= (unsigned)P; kk <<= 1) {
        for (unsigned jj = kk >> 1; jj > 0; jj >>= 1) {
            __syncthreads();
            for (unsigned i = t; i < (unsigned)P; i += 1024) {
                const unsigned ixj = i ^ jj;
                if (ixj > i) {
                    const unsigned long long x = F[i], y = F[ixj];
                    const bool up = ((i & kk) == 0);       // descending when up
                    if (up ? (x < y) : (x > y)) { F[i] = y; F[ixj] = x; }
                }
            }
        }
    }
    __syncthreads();

    float* oB = out + (size_t)b * NDET * 4;
    float* oS = out + (size_t)NBATCH * NDET * 4 + (size_t)b * NDET;
    float* oL = out + (size_t)NBATCH * NDET * 5 + (size_t)b * NDET;
    if (t < NDET) {
        const unsigned long long key = F[t];       // P >= 128 > NDET, zero-padded
        if (key != 0ULL) {
            const unsigned flat = ~(unsigned)key;
            const float score = __uint_as_float((unsigned)(key >> 32));
            const int np = flat / NFG;
            const int c  = (int)(flat - (unsigned)np * NFG) + 1;
            const float W = (float)imgsh[b * 2 + 1];
            const float H = (float)imgsh[b * 2 + 0];
            float bx1, by1, bx2, by2;
            decode_box(b, np, c, props, deltas, W, H, bx1, by1, bx2, by2);
            oB[t * 4 + 0] = bx1; oB[t * 4 + 1] = by1;
            oB[t * 4 + 2] = bx2; oB[t * 4 + 3] = by2;
            oS[t] = score;
            oL[t] = (float)c;
        } else {
            oB[t * 4 + 0] = 0.0f; oB[t * 4 + 1] = 0.0f;
            oB[t * 4 + 2] = 0.0f; oB[t * 4 + 3] = 0.0f;
            oS[t] = 0.0f; oL[t] = -1.0f;
        }
    }
}

extern "C" void kernel_launch(void* const* d_in, const int* in_sizes, int n_in,
                              void* d_out, int out_size, void* d_ws, size_t ws_size,
                              hipStream_t stream)
{
    const float* logits = (const float*)d_in[0];   // [B*N, 91]
    const float* deltas = (const float*)d_in[1];   // [B*N, 364]
    const float* props  = (const float*)d_in[2];   // [B, N, 4]
    const int*   imgsh  = (const int*)d_in[3];     // [B, 2]
    float* out = (float*)d_out;

    char* w = (char*)d_ws;
    float2* stats = (float2*)w;            w += (size_t)BN * sizeof(float2);       // 128 KB
    unsigned* mask = (unsigned*)w;         w += (size_t)3 * BN * sizeof(unsigned); // 192 KB
    unsigned long long* svKeys = (unsigned long long*)w;
    w += (size_t)NBATCH * SLOTS * sizeof(unsigned long long);                      // 288 KB
    int* clsCnt = (int*)w;                 w += 4096;                              // 360 ints
    int* clsOff = (int*)w;                 w += 4096;                              // 360 ints
    unsigned long long* cKeys = (unsigned long long*)w;
    w += (size_t)NBATCH * CSRCAP * sizeof(unsigned long long);                     // ~2.5 MB

    stats_mask_kernel<<<BN / 4, 256, 0, stream>>>(logits, props, deltas, imgsh, stats, mask);
    csr_kernel<<<NBATCH, 1024, 0, stream>>>(logits, stats, mask, clsCnt, clsOff, cKeys);
    class_nms_kernel<<<NBATCH * NFG, 256, 0, stream>>>(
        clsCnt, clsOff, cKeys, props, deltas, imgsh, svKeys);
    select_kernel<<<NBATCH, 1024, 0, stream>>>(svKeys, props, deltas, imgsh, out);
}

// Round 17
// 74.735 us; speedup vs baseline: 1.4775x; 1.4775x over previous
//
#include <hip/hip_runtime.h>
#include <math.h>
#include <float.h>
#include <limits.h>

#define NBATCH 4
#define NPROP  4096
#define NCLS   91
#define NFG    90
#define NDET   100
#define CCAP   1024            // per-(image,class) candidate cap (avg ~80; never hit)
#define BN     (NBATCH * NPROP)
#define SLOTS  (NFG * NDET)    // 9000 survivor slots per image
#define FCAP   16384           // fallback sort capacity (pow2 >= SLOTS)
#define CHUNK  128             // NMS matrix-walk chunk size
#define NWORD  128             // 4096 proposals / 32 bits

static __device__ __forceinline__ float clampf(float x, float lo, float hi) {
    return fminf(fmaxf(x, lo), hi);
}

// Decode + clip one (proposal, class) box. Identical arithmetic everywhere it is
// used -> bitwise-identical results (validated absmax 0.0, R1-R16).
static __device__ __forceinline__ void decode_box(int b, int np, int c,
    const float* __restrict__ props, const float* __restrict__ deltas,
    float W, float H, float& bx1, float& by1, float& bx2, float& by2)
{
    const float* pr = props + ((size_t)b * NPROP + np) * 4;
    const float x1 = pr[0], y1 = pr[1], x2 = pr[2], y2 = pr[3];
    const float w = x2 - x1, h = y2 - y1;
    const float cx = x1 + 0.5f * w, cy = y1 + 0.5f * h;
    const float* d = deltas + (((size_t)b * NPROP + np) * NCLS + c) * 4;
    const float BBC = 4.135166556742356f;   // log(1000/16)
    const float dx = d[0] / 10.0f;
    const float dy = d[1] / 10.0f;
    const float dw = fminf(d[2] / 5.0f, BBC);
    const float dh = fminf(d[3] / 5.0f, BBC);
    const float pcx = dx * w + cx;
    const float pcy = dy * h + cy;
    const float pw = expf(dw) * w;
    const float ph = expf(dh) * h;
    bx1 = clampf(pcx - 0.5f * pw, 0.0f, W);
    by1 = clampf(pcy - 0.5f * ph, 0.0f, H);
    bx2 = clampf(pcx + 0.5f * pw, 0.0f, W);
    by2 = clampf(pcy + 0.5f * ph, 0.0f, H);
}

// IoU > 0.5 predicate, identical float expression to all validated rounds.
static __device__ __forceinline__ bool iou_gt(const float4 S, const float4 Q, float aq)
{
    const float iw = fmaxf(fminf(S.z, Q.z) - fmaxf(S.x, Q.x), 0.0f);
    const float ih = fmaxf(fminf(S.w, Q.w) - fmaxf(S.y, Q.y), 0.0f);
    const float inter = iw * ih;
    const float as = (S.z - S.x) * (S.w - S.y);
    return inter / (as + aq - inter) > 0.5f;
}

// Block-wide exclusive scan over 1024 threads (wave shfl scan + wave totals).
static __device__ __forceinline__ int block_excl_scan(int v, int t, int* wtot)
{
    const int lane = t & 63, wid = t >> 6;
    int inc = v;
    #pragma unroll
    for (int s = 1; s < 64; s <<= 1) {
        const int u = __shfl_up(inc, s);
        if (lane >= s) inc += u;
    }
    if (lane == 63) wtot[wid] = inc;
    __syncthreads();
    int base = 0;
    for (int w2 = 0; w2 < wid; ++w2) base += wtot[w2];
    __syncthreads();                 // protect wtot for the next call
    return base + inc - v;
}

// Kernel 1: per-proposal softmax stats + 91-bit FINAL candidate mask.
// UNCHANGED from validated R9-R16.
__global__ __launch_bounds__(256) void stats_mask_kernel(
    const float* __restrict__ logits, const float* __restrict__ props,
    const float* __restrict__ deltas, const int* __restrict__ imgsh,
    float2* __restrict__ stats, unsigned* __restrict__ mask)
{
    const int wavei = threadIdx.x >> 6;
    const int lane  = threadIdx.x & 63;
    const int p = blockIdx.x * 4 + wavei;          // 0 .. B*N-1
    const int b = p >> 12;
    const int np = p & (NPROP - 1);
    const float* lrow = logits + (size_t)p * NCLS;

    const float a  = lrow[lane];
    const float a2 = (lane + 64 < NCLS) ? lrow[lane + 64] : -INFINITY;

    float m = fmaxf(a, a2);                        // level s=64
    #pragma unroll
    for (int s = 32; s > 0; s >>= 1) m = fmaxf(m, __shfl_down(m, s));
    m = __shfl(m, 0);

    const float e0 = expf(a - m);
    const float e1 = (lane + 64 < NCLS) ? expf(a2 - m) : 0.0f;
    float sum = e0 + e1;                           // level s=64
    #pragma unroll
    for (int s = 32; s > 0; s >>= 1) sum += __shfl_down(sum, s);
    sum = __shfl(sum, 0);

    const float W = (float)imgsh[b * 2 + 1];
    const float H = (float)imgsh[b * 2 + 0];

    bool pass0 = ((e0 / sum) > 0.05f) && (lane >= 1);     // class = lane (skip bg 0)
    if (pass0) {
        float bx1, by1, bx2, by2;
        decode_box(b, np, lane, props, deltas, W, H, bx1, by1, bx2, by2);
        pass0 = ((bx2 - bx1) >= 0.01f) && ((by2 - by1) >= 0.01f);
    }
    bool pass1 = ((e1 / sum) > 0.05f);                    // class = lane+64 (<= 90)
    if (pass1) {
        float bx1, by1, bx2, by2;
        decode_box(b, np, lane + 64, props, deltas, W, H, bx1, by1, bx2, by2);
        pass1 = ((bx2 - bx1) >= 0.01f) && ((by2 - by1) >= 0.01f);
    }

    const unsigned long long b0 = __ballot(pass0);        // classes 0..63
    const unsigned long long b1 = __ballot(pass1);        // classes 64..90

    if (lane == 0) {
        stats[p] = make_float2(m, sum);
        mask[p]          = (unsigned)b0;           // plane 0: classes  0..31
        mask[BN + p]     = (unsigned)(b0 >> 32);   // plane 1: classes 32..63
        mask[2 * BN + p] = (unsigned)b1;           // plane 2: classes 64..90
    }
}

// Kernel 2: parallel bit-transpose: mask planes [3][BN] -> maskT[b][c][128
// words] (bit np of word np>>5). 64 blocks x 256 thr, LDS only, NO atomics,
// fully deterministic. Each block transposes one 256-proposal slice.
__global__ __launch_bounds__(256) void maskt_kernel(
    const unsigned* __restrict__ mask, unsigned* __restrict__ maskT)
{
    const int blk = blockIdx.x;                    // 0..63
    const int b = blk >> 4;                        // image
    const int s = blk & 15;                        // slice of 256 proposals
    const int t = threadIdx.x;
    __shared__ unsigned lm[3 * 256];               // 3 KB

    #pragma unroll
    for (int j = 0; j < 3; ++j)
        lm[j * 256 + t] = mask[(size_t)j * BN + b * NPROP + s * 256 + t];
    __syncthreads();

    for (int idx = t; idx < NCLS * 8; idx += 256) {   // (class, word-in-slice)
        const int c = idx >> 3, w = idx & 7;
        const int plane = c >> 5, bitpos = c & 31;
        const unsigned* src = &lm[plane * 256 + w * 32];
        unsigned word = 0;
        #pragma unroll
        for (int k = 0; k < 32; ++k)
            word |= ((src[k] >> bitpos) & 1u) << k;
        maskT[((size_t)(b * NCLS + c)) * NWORD + s * 8 + w] = word;
    }
}

// Kernel 3: one block (256 threads) per (image, class). Gather = 512 B column
// read + popcount-scan enumeration (deterministic, no atomics) -> rank-sort
// (R15-validated) -> decode -> chunked suppression-matrix NMS (R14-validated).
__global__ __launch_bounds__(256) void class_nms_kernel(
    const float* __restrict__ logits, const float2* __restrict__ stats,
    const unsigned* __restrict__ maskT,
    const float* __restrict__ props, const float* __restrict__ deltas,
    const int* __restrict__ imgsh, unsigned long long* __restrict__ svKeys)
{
    const int blk  = blockIdx.x;                   // 0..359
    const int b    = blk / NFG;
    const int cm1  = blk % NFG;                    // class - 1
    const int c    = cm1 + 1;
    const int t    = threadIdx.x;
    const int lane = t & 63;

    __shared__ unsigned wbuf[NWORD];               // 512 B mask column
    __shared__ int wt2[2];
    __shared__ unsigned long long sk[CCAP];        // 8 KB, gathered (np order)
    __shared__ unsigned long long sks[CCAP];       // 8 KB, sorted desc
    __shared__ float4 sbox[CCAP];                  // 16 KB (boxes of sorted keys)
    __shared__ unsigned long long mrow[CHUNK][2];  // 2 KB suppression matrix
    __shared__ float4 sOwn[NDET];                  // accepted survivor boxes
    __shared__ unsigned long long sPreW[2];
    __shared__ int s_ns;

    const unsigned* col = maskT + ((size_t)(b * NCLS + c)) * NWORD;
    if (t < NWORD) wbuf[t] = col[t];
    __syncthreads();

    // popcount + exclusive scan over 128 words (2 waves) -> per-word offsets
    const int pc = (t < NWORD) ? __popc(wbuf[t]) : 0;
    int inc = pc;
    #pragma unroll
    for (int s = 1; s < 64; s <<= 1) {
        const int u = __shfl_up(inc, s);
        if (lane >= s) inc += u;
    }
    if (lane == 63 && (t >> 6) < 2) wt2[t >> 6] = inc;
    __syncthreads();
    const int ntot = wt2[0] + wt2[1];
    const int n = min(ntot, CCAP);
    if (n == 0) {
        for (int i = t; i < NDET; i += 256) svKeys[(size_t)blk * NDET + i] = 0ULL;
        return;
    }
    const int myoff = ((t >> 6) == 1 ? wt2[0] : 0) + inc - pc;

    // enumerate hits (deterministic positions, ascending np within word order)
    if (t < NWORD) {
        unsigned wv = wbuf[t];
        int o = myoff;
        while (wv) {
            const int k = __ffs(wv) - 1; wv &= wv - 1;
            const int np = t * 32 + k;
            const int p = b * NPROP + np;
            const float lg = logits[(size_t)p * NCLS + c];
            const float2 st = stats[p];
            const float score = expf(lg - st.x) / st.y;   // bitwise = kernel-1 value
            const unsigned flat = (unsigned)(np * NFG + cm1);
            const unsigned long long key =
                ((unsigned long long)__float_as_uint(score) << 32) | (unsigned)(~flat);
            if (o < CCAP) sk[o] = key;
            ++o;
        }
    }
    __syncthreads();

    // ---- rank-by-counting sort (descending); unique keys -> bijective ranks ----
    {
        unsigned long long myk[4];
        int rnk[4] = {0, 0, 0, 0};
        #pragma unroll
        for (int e = 0; e < 4; ++e)
            myk[e] = (t + e * 256 < n) ? sk[t + e * 256] : 0ULL;
        #pragma unroll 4
        for (int j = 0; j < n; ++j) {
            const unsigned long long kj = sk[j];
            #pragma unroll
            for (int e = 0; e < 4; ++e) rnk[e] += (kj > myk[e]) ? 1 : 0;
        }
        #pragma unroll
        for (int e = 0; e < 4; ++e)
            if (t + e * 256 < n) sks[rnk[e]] = myk[e];
    }
    __syncthreads();

    // ---- decode boxes ONCE for sorted candidates ----
    const float W = (float)imgsh[b * 2 + 1];
    const float H = (float)imgsh[b * 2 + 0];
    for (int i = t; i < n; i += 256) {
        const unsigned flat = ~(unsigned)sks[i];
        const int np = flat / NFG;                 // flat % NFG == cm1 by construction
        float bx1, by1, bx2, by2;
        decode_box(b, np, c, props, deltas, W, H, bx1, by1, bx2, by2);
        sbox[i] = make_float4(bx1, by1, bx2, by2);
    }
    if (t == 0) s_ns = 0;
    __syncthreads();

    // ---- chunked suppression-matrix greedy NMS (R14/R15-validated) ----
    int nsTot = 0;
    for (int cb = 0; cb < n && nsTot < NDET; cb += CHUNK) {
        const int C = min(CHUNK, n - cb);

        // (a) pre-suppression vs accepted survivors (free on chunk 1: nsTot==0)
        bool pre = false;
        if (t < C) {
            const float4 Q = sbox[cb + t];
            const float aq = (Q.z - Q.x) * (Q.w - Q.y);
            for (int l = 0; l < nsTot; ++l) {
                if (iou_gt(sOwn[l], Q, aq)) { pre = true; break; }
            }
        }
        const unsigned long long bal = __ballot(pre);
        if (t == 0)  sPreW[0] = bal;               // chunk idx 0..63
        if (t == 64) sPreW[1] = bal;               // chunk idx 64..127

        // (b) in-chunk suppression matrix: thread t -> row r = t>>1, word w = t&1
        {
            const int r = t >> 1, w = t & 1;
            unsigned long long word = 0ULL;
            if (r < C) {
                const float4 R = sbox[cb + r];     // row box (the earlier/suppressor)
                const int j0 = w * 64;
                const int jend = min(j0 + 64, C);
                for (int j = (j0 > r + 1 ? j0 : r + 1); j < jend; ++j) {
                    const float4 Q = sbox[cb + j];
                    const float aq = (Q.z - Q.x) * (Q.w - Q.y);
                    if (iou_gt(R, Q, aq)) word |= (1ULL << (j - j0));
                }
            }
            mrow[r][w] = word;
        }
        __syncthreads();

        // (c) scalar bitmask walk (thread 0): prefetched rows
        if (t == 0) {
            unsigned long long S0 = sPreW[0], S1 = sPreW[1];
            int ns = nsTot;
            unsigned long long r0 = mrow[0][0], r1 = mrow[0][1];
            for (int i = 0; i < C && ns < NDET; ++i) {
                const unsigned long long nr0 = (i + 1 < C) ? mrow[i + 1][0] : 0ULL;
                const unsigned long long nr1 = (i + 1 < C) ? mrow[i + 1][1] : 0ULL;
                const bool dead = (i < 64) ? ((S0 >> i) & 1ULL)
                                           : ((S1 >> (i - 64)) & 1ULL);
                if (!dead) {
                    sOwn[ns] = sbox[cb + i];
                    svKeys[(size_t)blk * NDET + ns] = sks[cb + i];
                    ++ns;
                    S0 |= r0; S1 |= r1;
                }
                r0 = nr0; r1 = nr1;
            }
            s_ns = ns;
        }
        __syncthreads();
        nsTot = s_ns;
    }

    // zero-fill unused survivor slots (deterministic)
    for (int i = nsTot + t; i < NDET; i += 256) svKeys[(size_t)blk * NDET + i] = 0ULL;
}

// Kernel 4: radix-select top-100. UNCHANGED from validated R12-R16.
__global__ __launch_bounds__(1024) void select_kernel(
    const unsigned long long* __restrict__ svKeys,
    const float* __restrict__ props, const float* __restrict__ deltas,
    const int* __restrict__ imgsh, float* __restrict__ out)
{
    const int b = blockIdx.x;
    const int t = threadIdx.x;
    __shared__ unsigned long long F[FCAP];         // 128 KB (sort buffer)
    __shared__ int hist[4096];                     // 16 KB
    __shared__ int wtot[16];
    __shared__ int s_T, s_above, s_total;

    if (t == 0) { s_T = -1; s_above = 0; s_total = 0; }
    #pragma unroll
    for (int j = 0; j < 4; ++j) hist[t + j * 1024] = 0;

    const unsigned long long* src = svKeys + (size_t)b * SLOTS;
    unsigned long long keys[9];
    #pragma unroll
    for (int j = 0; j < 9; ++j) {
        const int s = t + j * 1024;
        keys[j] = (s < SLOTS) ? src[s] : 0ULL;
    }
    __syncthreads();

    #pragma unroll
    for (int j = 0; j < 9; ++j) {
        if (keys[j] != 0ULL) atomicAdd(&hist[(unsigned)(keys[j] >> 52)], 1);
    }
    __syncthreads();

    {
        const int gbase = (1023 - t) * 4;
        const int s0 = hist[gbase] + hist[gbase + 1] + hist[gbase + 2] + hist[gbase + 3];
        const int pre = block_excl_scan(s0, t, wtot);   // counts in all higher buckets
        int acc = pre;
        for (int d = gbase + 3; d >= gbase; --d) {
            const int h = hist[d];
            if (acc < NDET && acc + h >= NDET) { s_T = d; s_above = acc; }  // unique
            acc += h;
        }
        if (t == 1023) s_total = acc;              // lowest group finishes the total
    }
    __syncthreads();

    const int T = s_T;
    const int total = s_total;
    const int n2 = (T < 0) ? total : (s_above + hist[T]);
    const bool fast = (n2 <= 2048);

    int mycnt = 0;
    #pragma unroll
    for (int j = 0; j < 9; ++j) {
        const unsigned long long k = keys[j];
        const bool m = (k != 0ULL) && (fast ? (T < 0 || (int)(k >> 52) >= T) : true);
        mycnt += m ? 1 : 0;
    }
    int off = block_excl_scan(mycnt, t, wtot);
    #pragma unroll
    for (int j = 0; j < 9; ++j) {
        const unsigned long long k = keys[j];
        const bool m = (k != 0ULL) && (fast ? (T < 0 || (int)(k >> 52) >= T) : true);
        if (m) F[off++] = k;
    }
    const int nsort = fast ? n2 : total;

    int P = 128; while (P < nsort) P <<= 1;        // pow2 pad, >= 128, <= FCAP
    for (int i = nsort + t; i < P; i += 1024) F[i] = 0ULL;

    for (unsigned kk = 2; kk <= (unsigned)P; kk <<= 1) {
        for (unsigned jj = kk >> 1; jj > 0; jj >>= 1) {
            __syncthreads();
            for (unsigned i = t; i < (unsigned)P; i += 1024) {
                const unsigned ixj = i ^ jj;
                if (ixj > i) {
                    const unsigned long long x = F[i], y = F[ixj];
                    const bool up = ((i & kk) == 0);       // descending when up
                    if (up ? (x < y) : (x > y)) { F[i] = y; F[ixj] = x; }
                }
            }
        }
    }
    __syncthreads();

    float* oB = out + (size_t)b * NDET * 4;
    float* oS = out + (size_t)NBATCH * NDET * 4 + (size_t)b * NDET;
    float* oL = out + (size_t)NBATCH * NDET * 5 + (size_t)b * NDET;
    if (t < NDET) {
        const unsigned long long key = F[t];       // P >= 128 > NDET, zero-padded
        if (key != 0ULL) {
            const unsigned flat = ~(unsigned)key;
            const float score = __uint_as_float((unsigned)(key >> 32));
            const int np = flat / NFG;
            const int c  = (int)(flat - (unsigned)np * NFG) + 1;
            const float W = (float)imgsh[b * 2 + 1];
            const float H = (float)imgsh[b * 2 + 0];
            float bx1, by1, bx2, by2;
            decode_box(b, np, c, props, deltas, W, H, bx1, by1, bx2, by2);
            oB[t * 4 + 0] = bx1; oB[t * 4 + 1] = by1;
            oB[t * 4 + 2] = bx2; oB[t * 4 + 3] = by2;
            oS[t] = score;
            oL[t] = (float)c;
        } else {
            oB[t * 4 + 0] = 0.0f; oB[t * 4 + 1] = 0.0f;
            oB[t * 4 + 2] = 0.0f; oB[t * 4 + 3] = 0.0f;
            oS[t] = 0.0f; oL[t] = -1.0f;
        }
    }
}

extern "C" void kernel_launch(void* const* d_in, const int* in_sizes, int n_in,
                              void* d_out, int out_size, void* d_ws, size_t ws_size,
                              hipStream_t stream)
{
    const float* logits = (const float*)d_in[0];   // [B*N, 91]
    const float* deltas = (const float*)d_in[1];   // [B*N, 364]
    const float* props  = (const float*)d_in[2];   // [B, N, 4]
    const int*   imgsh  = (const int*)d_in[3];     // [B, 2]
    float* out = (float*)d_out;

    char* w = (char*)d_ws;
    float2* stats = (float2*)w;            w += (size_t)BN * sizeof(float2);       // 128 KB
    unsigned* mask = (unsigned*)w;         w += (size_t)3 * BN * sizeof(unsigned); // 192 KB
    unsigned long long* svKeys = (unsigned long long*)w;
    w += (size_t)NBATCH * SLOTS * sizeof(unsigned long long);                      // 288 KB
    unsigned* maskT = (unsigned*)w;
    w += (size_t)NBATCH * NCLS * NWORD * sizeof(unsigned);                         // 186 KB

    stats_mask_kernel<<<BN / 4, 256, 0, stream>>>(logits, props, deltas, imgsh, stats, mask);
    maskt_kernel<<<NBATCH * 16, 256, 0, stream>>>(mask, maskT);
    class_nms_kernel<<<NBATCH * NFG, 256, 0, stream>>>(
        logits, stats, maskT, props, deltas, imgsh, svKeys);
    select_kernel<<<NBATCH, 1024, 0, stream>>>(svKeys, props, deltas, imgsh, out);
}